// Round 2
// baseline (595.241 us; speedup 1.0000x reference)
//
#include <hip/hip_runtime.h>
#include <hip/hip_bf16.h>
#include <cstdint>

// ---------------------------------------------------------------------------
// Types
// ---------------------------------------------------------------------------
typedef short bf16x8 __attribute__((ext_vector_type(8)));     // 8 bf16 = 4 VGPRs (MFMA A/B frag)
typedef float f32x4  __attribute__((ext_vector_type(4)));     // MFMA C/D frag
typedef unsigned short u16x8 __attribute__((ext_vector_type(8)));
typedef unsigned short u16x4 __attribute__((ext_vector_type(4)));

#define SEQ    2048
#define BATCH  4
#define DMODEL 1024
#define NHEAD  16
#define DKH    64
#define MROWS  (BATCH * SEQ)      // 8192

__device__ __forceinline__ unsigned short f2bf(float f) {
  union { float f; uint32_t u; } x; x.f = f;
  uint32_t r = (x.u + 0x7fffu + ((x.u >> 16) & 1u)) >> 16;   // RNE
  return (unsigned short)r;
}
__device__ __forceinline__ float bf2f(unsigned short u) {
  union { uint32_t u; float f; } x; x.u = ((uint32_t)u) << 16;
  return x.f;
}
__device__ __forceinline__ void gload_lds16(const void* g, void* l) {
  __builtin_amdgcn_global_load_lds(
      (const __attribute__((address_space(1))) void*)g,
      (__attribute__((address_space(3))) void*)l, 16, 0, 0);
}

// ---------------------------------------------------------------------------
// fp32 -> bf16 cast (vectorized, n multiple of 1024)
// ---------------------------------------------------------------------------
__global__ __launch_bounds__(256) void cast_f32_bf16(
    const float* __restrict__ in, unsigned short* __restrict__ out, int n) {
  int i = (blockIdx.x * 256 + threadIdx.x) * 4;
  if (i + 3 < n) {
    float4 v = *(const float4*)(in + i);
    u16x4 o;
    o[0] = f2bf(v.x); o[1] = f2bf(v.y); o[2] = f2bf(v.z); o[3] = f2bf(v.w);
    *(u16x4*)(out + i) = o;
  }
}

// ---------------------------------------------------------------------------
// adaLN embedding: emb[b][0:2048] = gelu(t[b]) @ ada_w.T + ada_b
// grid (8, 4) x 256
// ---------------------------------------------------------------------------
__global__ __launch_bounds__(256) void ada_emb_kernel(
    const float* __restrict__ t, const float* __restrict__ ada_w,
    const float* __restrict__ ada_b, float* __restrict__ emb) {
  int b = blockIdx.y;
  int j = blockIdx.x * 256 + threadIdx.x;          // 0..2047
  __shared__ float g[64];
  if (threadIdx.x < 64) {
    float x = t[b * 64 + threadIdx.x];
    g[threadIdx.x] = x * 0.5f * (1.0f + erff(x * 0.70710678118654752f)); // exact gelu
  }
  __syncthreads();
  float acc = ada_b[j];
  const float* wr = ada_w + (size_t)j * 64;
  #pragma unroll
  for (int i = 0; i < 64; ++i) acc += g[i] * wr[i];
  emb[b * 2048 + j] = acc;
}

// ---------------------------------------------------------------------------
// adaLN: x = LN(q)*(1+scale)+shift, stored bf16 (also the residual)
// one block per row; 256 threads x 4 elems
// ---------------------------------------------------------------------------
__global__ __launch_bounds__(256) void adaln_kernel(
    const float* __restrict__ q, const float* __restrict__ emb,
    unsigned short* __restrict__ xbf) {
  int row = blockIdx.x;                     // 0..8191
  int b = row >> 11;
  int tid = threadIdx.x;
  float4 x = ((const float4*)(q + (size_t)row * DMODEL))[tid];
  float s  = x.x + x.y + x.z + x.w;
  float s2 = x.x * x.x + x.y * x.y + x.z * x.z + x.w * x.w;
  #pragma unroll
  for (int off = 32; off > 0; off >>= 1) {
    s  += __shfl_down(s, off);
    s2 += __shfl_down(s2, off);
  }
  __shared__ float red[8];
  int w = tid >> 6;
  if ((tid & 63) == 0) { red[w * 2] = s; red[w * 2 + 1] = s2; }
  __syncthreads();
  s  = red[0] + red[2] + red[4] + red[6];
  s2 = red[1] + red[3] + red[5] + red[7];
  float mean = s * (1.0f / 1024.0f);
  float var  = s2 * (1.0f / 1024.0f) - mean * mean;
  float rs = rsqrtf(var + 1e-5f);
  float4 sc = ((const float4*)(emb + (size_t)b * 2048))[tid];
  float4 sh = ((const float4*)(emb + (size_t)b * 2048 + 1024))[tid];
  u16x4 o;
  o[0] = f2bf((x.x - mean) * rs * (1.0f + sc.x) + sh.x);
  o[1] = f2bf((x.y - mean) * rs * (1.0f + sc.y) + sh.y);
  o[2] = f2bf((x.z - mean) * rs * (1.0f + sc.z) + sh.z);
  o[3] = f2bf((x.w - mean) * rs * (1.0f + sc.w) + sh.w);
  ((u16x4*)(xbf + (size_t)row * DMODEL))[tid] = o;
}

// ---------------------------------------------------------------------------
// GEMM: C[M,N] = A[M,K] @ Bw[N,K]^T   (both K-contiguous, bf16, fp32 accum)
// M=8192, N=1024, K=1024. 128x128 tile, BK=64, 4 waves (2x2 of 64x64).
// MODE 0: write bf16 C.  MODE 1: write f32 C + residual(bf16).
// grid (N/128=8, M/128=64) x 256
// ---------------------------------------------------------------------------
template <int MODE>
__global__ __launch_bounds__(256) void gemm_bt(
    const unsigned short* __restrict__ A, const unsigned short* __restrict__ Bw,
    unsigned short* __restrict__ Cb, const unsigned short* __restrict__ resid,
    float* __restrict__ Cf) {
  __shared__ __align__(16) unsigned short Al[128 * 64];
  __shared__ __align__(16) unsigned short Bl[128 * 64];
  int tid = threadIdx.x;
  int lane = tid & 63, w = tid >> 6;
  int l15 = lane & 15, l16 = lane >> 4;
  int m0 = blockIdx.y * 128, n0 = blockIdx.x * 128;
  int wr = w >> 1, wc = w & 1;

  f32x4 acc[4][4];
  #pragma unroll
  for (int m = 0; m < 4; ++m)
    #pragma unroll
    for (int n = 0; n < 4; ++n) acc[m][n] = {0.f, 0.f, 0.f, 0.f};

  const unsigned short* Ab = A + (size_t)m0 * 1024;
  const unsigned short* Bb = Bw + (size_t)n0 * 1024;

  for (int kt = 0; kt < 16; ++kt) {
    int k0 = kt * 64;
    #pragma unroll
    for (int it = 0; it < 4; ++it) {
      int c = it * 256 + tid;
      int r = c >> 3, cg = c & 7;
      gload_lds16(Ab + (size_t)r * 1024 + k0 + cg * 8, &Al[c * 8]);
    }
    #pragma unroll
    for (int it = 0; it < 4; ++it) {
      int c = it * 256 + tid;
      int r = c >> 3, cg = c & 7;
      gload_lds16(Bb + (size_t)r * 1024 + k0 + cg * 8, &Bl[c * 8]);
    }
    __syncthreads();          // drains vmcnt -> staged data visible
    #pragma unroll
    for (int kk = 0; kk < 2; ++kk) {
      bf16x8 af[4], bfr[4];
      #pragma unroll
      for (int m = 0; m < 4; ++m)
        af[m] = *(const bf16x8*)&Al[(wr * 64 + m * 16 + l15) * 64 + kk * 32 + l16 * 8];
      #pragma unroll
      for (int n = 0; n < 4; ++n)
        bfr[n] = *(const bf16x8*)&Bl[(wc * 64 + n * 16 + l15) * 64 + kk * 32 + l16 * 8];
      #pragma unroll
      for (int m = 0; m < 4; ++m)
        #pragma unroll
        for (int n = 0; n < 4; ++n)
          acc[m][n] = __builtin_amdgcn_mfma_f32_16x16x32_bf16(af[m], bfr[n], acc[m][n], 0, 0, 0);
    }
    __syncthreads();
  }

  #pragma unroll
  for (int m = 0; m < 4; ++m) {
    #pragma unroll
    for (int r = 0; r < 4; ++r) {
      int row = m0 + wr * 64 + m * 16 + l16 * 4 + r;
      size_t base = (size_t)row * 1024 + n0 + wc * 64 + l15;
      #pragma unroll
      for (int n = 0; n < 4; ++n) {
        float val = acc[m][n][r];
        if (MODE == 0) {
          Cb[base + n * 16] = f2bf(val);
        } else {
          Cf[base + n * 16] = val + bf2f(resid[base + n * 16]);
        }
      }
    }
  }
}

// ---------------------------------------------------------------------------
// Flash attention: one block = (b, h, 64 q-rows); 4 waves x 16 rows each.
// KV tiles of 64. Scores via mfma(Q, K); online softmax with 16-lane-group
// shuffles; P -> per-wave LDS -> A-frag; PV via mfma(P, V^T-staged).
// grid (32, 16, 4) x 256
// ---------------------------------------------------------------------------
__global__ __launch_bounds__(256) void attn_kernel(
    const unsigned short* __restrict__ Q, const unsigned short* __restrict__ K,
    const unsigned short* __restrict__ V, unsigned short* __restrict__ O) {
  int tid = threadIdx.x;
  int lane = tid & 63, w = tid >> 6;
  int l15 = lane & 15, l16 = lane >> 4;
  int qt = blockIdx.x, h = blockIdx.y, b = blockIdx.z;

  __shared__ __align__(16) unsigned short Kl[64 * 64];
  __shared__ __align__(16) unsigned short VT[64 * 64];
  __shared__ __align__(16) unsigned short Pl[4][16 * 64];

  size_t hb = (size_t)b * SEQ * DMODEL + (size_t)h * DKH;
  int qrow = qt * 64 + w * 16;

  bf16x8 qf[2];
  qf[0] = *(const bf16x8*)(Q + hb + (size_t)(qrow + l15) * DMODEL + 0  + l16 * 8);
  qf[1] = *(const bf16x8*)(Q + hb + (size_t)(qrow + l15) * DMODEL + 32 + l16 * 8);

  float m_r[4], l_r[4];
  f32x4 oacc[4];
  #pragma unroll
  for (int r = 0; r < 4; ++r) { m_r[r] = -INFINITY; l_r[r] = 0.f; }
  #pragma unroll
  for (int n = 0; n < 4; ++n) oacc[n] = {0.f, 0.f, 0.f, 0.f};

  const float sc = 1.0f / 256.0f;   // 1/TEMPERATURE

  for (int t = 0; t < SEQ / 64; ++t) {
    int kv0 = t * 64;
    // stage K tile (64x64) via async global->LDS
    #pragma unroll
    for (int it = 0; it < 2; ++it) {
      int c = it * 256 + tid;
      int r = c >> 3, cg = c & 7;
      gload_lds16(K + hb + (size_t)(kv0 + r) * DMODEL + cg * 8, &Kl[c * 8]);
    }
    // stage V^T tile (dk-major) via register transpose
    {
      int kv = tid & 63, dk0 = (tid >> 6) * 16;
      const unsigned short* vp = V + hb + (size_t)(kv0 + kv) * DMODEL + dk0;
      u16x8 v0 = *(const u16x8*)vp;
      u16x8 v1 = *(const u16x8*)(vp + 8);
      #pragma unroll
      for (int e = 0; e < 8; ++e) VT[(dk0 + e) * 64 + kv] = v0[e];
      #pragma unroll
      for (int e = 0; e < 8; ++e) VT[(dk0 + 8 + e) * 64 + kv] = v1[e];
    }
    __syncthreads();

    // scores S[16q x 64kv]
    f32x4 sa[4];
    #pragma unroll
    for (int n = 0; n < 4; ++n) sa[n] = {0.f, 0.f, 0.f, 0.f};
    #pragma unroll
    for (int kk = 0; kk < 2; ++kk) {
      #pragma unroll
      for (int n = 0; n < 4; ++n) {
        bf16x8 kf = *(const bf16x8*)&Kl[(n * 16 + l15) * 64 + kk * 32 + l16 * 8];
        sa[n] = __builtin_amdgcn_mfma_f32_16x16x32_bf16(qf[kk], kf, sa[n], 0, 0, 0);
      }
    }
    #pragma unroll
    for (int n = 0; n < 4; ++n)
      #pragma unroll
      for (int r = 0; r < 4; ++r) sa[n][r] *= sc;

    // online softmax (rows live in 16-lane groups)
    float corr[4];
    #pragma unroll
    for (int r = 0; r < 4; ++r) {
      float mx = fmaxf(fmaxf(sa[0][r], sa[1][r]), fmaxf(sa[2][r], sa[3][r]));
      #pragma unroll
      for (int msk = 1; msk < 16; msk <<= 1) mx = fmaxf(mx, __shfl_xor(mx, msk));
      float mn = fmaxf(m_r[r], mx);
      corr[r] = __expf(m_r[r] - mn);     // exp(-inf)=0 on first tile
      m_r[r] = mn;
    }
    float rs[4];
    #pragma unroll
    for (int n = 0; n < 4; ++n)
      #pragma unroll
      for (int r = 0; r < 4; ++r) sa[n][r] = __expf(sa[n][r] - m_r[r]);
    #pragma unroll
    for (int r = 0; r < 4; ++r) {
      rs[r] = sa[0][r] + sa[1][r] + sa[2][r] + sa[3][r];
      #pragma unroll
      for (int msk = 1; msk < 16; msk <<= 1) rs[r] += __shfl_xor(rs[r], msk);
      l_r[r] = l_r[r] * corr[r] + rs[r];
    }
    #pragma unroll
    for (int n = 0; n < 4; ++n)
      #pragma unroll
      for (int r = 0; r < 4; ++r) oacc[n][r] *= corr[r];

    // P -> LDS (D-layout scatter), read back as A-frags
    #pragma unroll
    for (int n = 0; n < 4; ++n)
      #pragma unroll
      for (int r = 0; r < 4; ++r)
        Pl[w][(l16 * 4 + r) * 64 + n * 16 + l15] = f2bf(sa[n][r]);

    bf16x8 pf[2];
    pf[0] = *(const bf16x8*)&Pl[w][l15 * 64 + 0  + l16 * 8];
    pf[1] = *(const bf16x8*)&Pl[w][l15 * 64 + 32 + l16 * 8];

    #pragma unroll
    for (int kk = 0; kk < 2; ++kk) {
      #pragma unroll
      for (int n = 0; n < 4; ++n) {
        bf16x8 vf = *(const bf16x8*)&VT[(n * 16 + l15) * 64 + kk * 32 + l16 * 8];
        oacc[n] = __builtin_amdgcn_mfma_f32_16x16x32_bf16(pf[kk], vf, oacc[n], 0, 0, 0);
      }
    }
    __syncthreads();
  }

  #pragma unroll
  for (int r = 0; r < 4; ++r) {
    float inv = 1.0f / l_r[r];
    #pragma unroll
    for (int n = 0; n < 4; ++n)
      O[hb + (size_t)(qrow + l16 * 4 + r) * DMODEL + n * 16 + l15] = f2bf(oacc[n][r] * inv);
  }
}

// ---------------------------------------------------------------------------
// Workspace layout (bytes)
// ---------------------------------------------------------------------------
static constexpr size_t EMB_OFF = 0;                         // 4*2048*4 = 32 KB
static constexpr size_t WQ_OFF  = 32768;
static constexpr size_t WK_OFF  = WQ_OFF + 2097152;
static constexpr size_t WV_OFF  = WK_OFF + 2097152;
static constexpr size_t WFC_OFF = WV_OFF + 2097152;
static constexpr size_t XBF_OFF = WFC_OFF + 2097152;         // 16 MB
static constexpr size_t KBF_OFF = XBF_OFF + 16777216;        // 16 MB
static constexpr size_t VBF_OFF = KBF_OFF + 16777216;        // 16 MB
static constexpr size_t QH_OFF  = VBF_OFF + 16777216;        // 16 MB
static constexpr size_t KH_OFF  = QH_OFF + 16777216;         // 16 MB
static constexpr size_t VH_OFF  = KH_OFF + 16777216;         // 16 MB
static constexpr size_t ATTN_OFF = KBF_OFF;                  // alias (k_bf dead after kh GEMM)

extern "C" void kernel_launch(void* const* d_in, const int* in_sizes, int n_in,
                              void* d_out, int out_size, void* d_ws, size_t ws_size,
                              hipStream_t stream) {
  const float* q     = (const float*)d_in[0];
  const float* k     = (const float*)d_in[1];
  const float* v     = (const float*)d_in[2];
  const float* t     = (const float*)d_in[3];
  const float* w_q   = (const float*)d_in[4];
  const float* w_k   = (const float*)d_in[5];
  const float* w_v   = (const float*)d_in[6];
  const float* w_fc  = (const float*)d_in[7];
  const float* ada_w = (const float*)d_in[8];
  const float* ada_b = (const float*)d_in[9];

  char* ws = (char*)d_ws;
  float* emb           = (float*)(ws + EMB_OFF);
  unsigned short* wqb  = (unsigned short*)(ws + WQ_OFF);
  unsigned short* wkb  = (unsigned short*)(ws + WK_OFF);
  unsigned short* wvb  = (unsigned short*)(ws + WV_OFF);
  unsigned short* wfcb = (unsigned short*)(ws + WFC_OFF);
  unsigned short* xbf  = (unsigned short*)(ws + XBF_OFF);
  unsigned short* kbf  = (unsigned short*)(ws + KBF_OFF);
  unsigned short* vbf  = (unsigned short*)(ws + VBF_OFF);
  unsigned short* qh   = (unsigned short*)(ws + QH_OFF);
  unsigned short* kh   = (unsigned short*)(ws + KH_OFF);
  unsigned short* vh   = (unsigned short*)(ws + VH_OFF);
  unsigned short* attn = (unsigned short*)(ws + ATTN_OFF);
  float* outf          = (float*)d_out;

  // 1) casts to bf16
  cast_f32_bf16<<<1024, 256, 0, stream>>>(w_q,  wqb,  1048576);
  cast_f32_bf16<<<1024, 256, 0, stream>>>(w_k,  wkb,  1048576);
  cast_f32_bf16<<<1024, 256, 0, stream>>>(w_v,  wvb,  1048576);
  cast_f32_bf16<<<1024, 256, 0, stream>>>(w_fc, wfcb, 1048576);
  cast_f32_bf16<<<8192, 256, 0, stream>>>(k, kbf, 8388608);
  cast_f32_bf16<<<8192, 256, 0, stream>>>(v, vbf, 8388608);

  // 2) adaLN scale/shift embedding
  ada_emb_kernel<<<dim3(8, 4), 256, 0, stream>>>(t, ada_w, ada_b, emb);

  // 3) adaLN on q -> x (bf16, also residual)
  adaln_kernel<<<8192, 256, 0, stream>>>(q, emb, xbf);

  // 4) QKV projections
  gemm_bt<0><<<dim3(8, 64), 256, 0, stream>>>(xbf, wqb, qh, nullptr, nullptr);
  gemm_bt<0><<<dim3(8, 64), 256, 0, stream>>>(kbf, wkb, kh, nullptr, nullptr);
  gemm_bt<0><<<dim3(8, 64), 256, 0, stream>>>(vbf, wvb, vh, nullptr, nullptr);

  // 5) attention
  attn_kernel<<<dim3(32, 16, 4), 256, 0, stream>>>(qh, kh, vh, attn);

  // 6) out-proj + residual (fp32 out)
  gemm_bt<1><<<dim3(8, 64), 256, 0, stream>>>(attn, wfcb, nullptr, xbf, outf);
}

// Round 3
// 460.018 us; speedup vs baseline: 1.2940x; 1.2940x over previous
//
#include <hip/hip_runtime.h>
#include <hip/hip_bf16.h>
#include <cstdint>

// ---------------------------------------------------------------------------
// Types
// ---------------------------------------------------------------------------
typedef short bf16x8 __attribute__((ext_vector_type(8)));     // 8 bf16 = 4 VGPRs (MFMA A/B frag)
typedef float f32x4  __attribute__((ext_vector_type(4)));     // MFMA C/D frag
typedef unsigned short u16x8 __attribute__((ext_vector_type(8)));
typedef unsigned short u16x4 __attribute__((ext_vector_type(4)));

#define SEQ    2048
#define BATCH  4
#define DMODEL 1024
#define NHEAD  16
#define DKH    64
#define MROWS  (BATCH * SEQ)      // 8192

__device__ __forceinline__ unsigned short f2bf(float f) {
  union { float f; uint32_t u; } x; x.f = f;
  uint32_t r = (x.u + 0x7fffu + ((x.u >> 16) & 1u)) >> 16;   // RNE
  return (unsigned short)r;
}
__device__ __forceinline__ float bf2f(unsigned short u) {
  union { uint32_t u; float f; } x; x.u = ((uint32_t)u) << 16;
  return x.f;
}
__device__ __forceinline__ void gload_lds16(const void* g, void* l) {
  __builtin_amdgcn_global_load_lds(
      (const __attribute__((address_space(1))) void*)g,
      (__attribute__((address_space(3))) void*)l, 16, 0, 0);
}

// ---------------------------------------------------------------------------
// fp32 -> bf16 cast (vectorized, n multiple of 1024)
// ---------------------------------------------------------------------------
__global__ __launch_bounds__(256) void cast_f32_bf16(
    const float* __restrict__ in, unsigned short* __restrict__ out, int n) {
  int i = (blockIdx.x * 256 + threadIdx.x) * 4;
  if (i + 3 < n) {
    float4 v = *(const float4*)(in + i);
    u16x4 o;
    o[0] = f2bf(v.x); o[1] = f2bf(v.y); o[2] = f2bf(v.z); o[3] = f2bf(v.w);
    *(u16x4*)(out + i) = o;
  }
}

// ---------------------------------------------------------------------------
// adaLN embedding: emb[b][0:2048] = gelu(t[b]) @ ada_w.T + ada_b
// grid (8, 4) x 256
// ---------------------------------------------------------------------------
__global__ __launch_bounds__(256) void ada_emb_kernel(
    const float* __restrict__ t, const float* __restrict__ ada_w,
    const float* __restrict__ ada_b, float* __restrict__ emb) {
  int b = blockIdx.y;
  int j = blockIdx.x * 256 + threadIdx.x;          // 0..2047
  __shared__ float g[64];
  if (threadIdx.x < 64) {
    float x = t[b * 64 + threadIdx.x];
    g[threadIdx.x] = x * 0.5f * (1.0f + erff(x * 0.70710678118654752f)); // exact gelu
  }
  __syncthreads();
  float acc = ada_b[j];
  const float* wr = ada_w + (size_t)j * 64;
  #pragma unroll
  for (int i = 0; i < 64; ++i) acc += g[i] * wr[i];
  emb[b * 2048 + j] = acc;
}

// ---------------------------------------------------------------------------
// adaLN: x = LN(q)*(1+scale)+shift, stored bf16 (also the residual)
// one block per row; 256 threads x 4 elems
// ---------------------------------------------------------------------------
__global__ __launch_bounds__(256) void adaln_kernel(
    const float* __restrict__ q, const float* __restrict__ emb,
    unsigned short* __restrict__ xbf) {
  int row = blockIdx.x;                     // 0..8191
  int b = row >> 11;
  int tid = threadIdx.x;
  float4 x = ((const float4*)(q + (size_t)row * DMODEL))[tid];
  float s  = x.x + x.y + x.z + x.w;
  float s2 = x.x * x.x + x.y * x.y + x.z * x.z + x.w * x.w;
  #pragma unroll
  for (int off = 32; off > 0; off >>= 1) {
    s  += __shfl_down(s, off);
    s2 += __shfl_down(s2, off);
  }
  __shared__ float red[8];
  int w = tid >> 6;
  if ((tid & 63) == 0) { red[w * 2] = s; red[w * 2 + 1] = s2; }
  __syncthreads();
  s  = red[0] + red[2] + red[4] + red[6];
  s2 = red[1] + red[3] + red[5] + red[7];
  float mean = s * (1.0f / 1024.0f);
  float var  = s2 * (1.0f / 1024.0f) - mean * mean;
  float rs = rsqrtf(var + 1e-5f);
  float4 sc = ((const float4*)(emb + (size_t)b * 2048))[tid];
  float4 sh = ((const float4*)(emb + (size_t)b * 2048 + 1024))[tid];
  u16x4 o;
  o[0] = f2bf((x.x - mean) * rs * (1.0f + sc.x) + sh.x);
  o[1] = f2bf((x.y - mean) * rs * (1.0f + sc.y) + sh.y);
  o[2] = f2bf((x.z - mean) * rs * (1.0f + sc.z) + sh.z);
  o[3] = f2bf((x.w - mean) * rs * (1.0f + sc.w) + sh.w);
  ((u16x4*)(xbf + (size_t)row * DMODEL))[tid] = o;
}

// ---------------------------------------------------------------------------
// GEMM: C[M,N] = A[M,K] @ Bw[N,K]^T   (both K-contiguous, bf16, fp32 accum)
// M=8192, N=1024, K=1024. 128x128 tile, BK=64, 4 waves (2x2 of 64x64).
// MODE 0: write bf16 C.  MODE 1: write f32 C + residual(bf16).
// grid (N/128=8, M/128=64) x 256
// ---------------------------------------------------------------------------
template <int MODE>
__global__ __launch_bounds__(256) void gemm_bt(
    const unsigned short* __restrict__ A, const unsigned short* __restrict__ Bw,
    unsigned short* __restrict__ Cb, const unsigned short* __restrict__ resid,
    float* __restrict__ Cf) {
  __shared__ __align__(16) unsigned short Al[128 * 64];
  __shared__ __align__(16) unsigned short Bl[128 * 64];
  int tid = threadIdx.x;
  int lane = tid & 63, w = tid >> 6;
  int l15 = lane & 15, l16 = lane >> 4;
  int m0 = blockIdx.y * 128, n0 = blockIdx.x * 128;
  int wr = w >> 1, wc = w & 1;

  f32x4 acc[4][4];
  #pragma unroll
  for (int m = 0; m < 4; ++m)
    #pragma unroll
    for (int n = 0; n < 4; ++n) acc[m][n] = {0.f, 0.f, 0.f, 0.f};

  const unsigned short* Ab = A + (size_t)m0 * 1024;
  const unsigned short* Bb = Bw + (size_t)n0 * 1024;

  for (int kt = 0; kt < 16; ++kt) {
    int k0 = kt * 64;
    #pragma unroll
    for (int it = 0; it < 4; ++it) {
      int c = it * 256 + tid;
      int r = c >> 3, cg = c & 7;
      gload_lds16(Ab + (size_t)r * 1024 + k0 + cg * 8, &Al[c * 8]);
    }
    #pragma unroll
    for (int it = 0; it < 4; ++it) {
      int c = it * 256 + tid;
      int r = c >> 3, cg = c & 7;
      gload_lds16(Bb + (size_t)r * 1024 + k0 + cg * 8, &Bl[c * 8]);
    }
    __syncthreads();          // drains vmcnt -> staged data visible
    #pragma unroll
    for (int kk = 0; kk < 2; ++kk) {
      bf16x8 af[4], bfr[4];
      #pragma unroll
      for (int m = 0; m < 4; ++m)
        af[m] = *(const bf16x8*)&Al[(wr * 64 + m * 16 + l15) * 64 + kk * 32 + l16 * 8];
      #pragma unroll
      for (int n = 0; n < 4; ++n)
        bfr[n] = *(const bf16x8*)&Bl[(wc * 64 + n * 16 + l15) * 64 + kk * 32 + l16 * 8];
      #pragma unroll
      for (int m = 0; m < 4; ++m)
        #pragma unroll
        for (int n = 0; n < 4; ++n)
          acc[m][n] = __builtin_amdgcn_mfma_f32_16x16x32_bf16(af[m], bfr[n], acc[m][n], 0, 0, 0);
    }
    __syncthreads();
  }

  #pragma unroll
  for (int m = 0; m < 4; ++m) {
    #pragma unroll
    for (int r = 0; r < 4; ++r) {
      int row = m0 + wr * 64 + m * 16 + l16 * 4 + r;
      size_t base = (size_t)row * 1024 + n0 + wc * 64 + l15;
      #pragma unroll
      for (int n = 0; n < 4; ++n) {
        float val = acc[m][n][r];
        if (MODE == 0) {
          Cb[base + n * 16] = f2bf(val);
        } else {
          Cf[base + n * 16] = val + bf2f(resid[base + n * 16]);
        }
      }
    }
  }
}

// ---------------------------------------------------------------------------
// Flash attention v2: one block = (b, h, 128 q-rows); 4 waves x 32 rows each.
// Swapped-operand structure:
//   S^T = mfma(K_frag, Q_frag)  -> lane holds one q-col (q = l15), 16 k-vals
//   softmax: 15 in-lane ops + 2 shfl_xor (16, 32)  -- state is lane-local
//   O^T = mfma(VT_frag, PT_frag) -> accumulator col = q = l15 (corr/l lane-local)
// All LDS tiles XOR-swizzled at 16B-chunk granularity (chunk ^= row&7):
//   K staged via global_load_lds with PRE-SWIZZLED global source (rule 21),
//   VT / Pl reg-staged with swizzled write addresses; all reads same XOR.
// Grid: 1024 blocks 1D with bijective XCD swizzle so the 16 q-tiles of one
// (b,h) share an XCD (K/V set 8 x 512KB = 4MB = one L2).
// ---------------------------------------------------------------------------
__global__ __launch_bounds__(256) void attn_kernel(
    const unsigned short* __restrict__ Q, const unsigned short* __restrict__ K,
    const unsigned short* __restrict__ V, unsigned short* __restrict__ O) {
  int tid = threadIdx.x;
  int lane = tid & 63, w = tid >> 6;
  int l15 = lane & 15, l16 = lane >> 4;
  int sw7 = l15 & 7;                       // read-side swizzle key (row&7)

  // XCD-aware decode: XCD k gets contiguous e-range -> 8 (b,h) pairs each
  int wgid = blockIdx.x;
  int e = (wgid & 7) * 128 + (wgid >> 3);
  int qt = e & 15, h = (e >> 4) & 15, b = e >> 8;

  __shared__ __align__(16) unsigned short Kl[64 * 64];      // 8 KB swizzled
  __shared__ __align__(16) unsigned short VT[64 * 64];      // 8 KB swizzled (d-major)
  __shared__ __align__(16) unsigned short Pl[4][16 * 64];   // 8 KB per-wave P^T

  size_t hb = (size_t)b * SEQ * DMODEL + (size_t)h * DKH;
  int qrow = qt * 128 + w * 32;

  // Q fragments (B-frag: col=q=l15, k = l16*8+j), 2 q-subtiles x 2 k-halves
  bf16x8 qf[2][2];
  #pragma unroll
  for (int qs = 0; qs < 2; ++qs)
    #pragma unroll
    for (int kk = 0; kk < 2; ++kk)
      qf[qs][kk] = *(const bf16x8*)(Q + hb + (size_t)(qrow + qs * 16 + l15) * DMODEL + kk * 32 + l16 * 8);

  float m_s[2] = {-INFINITY, -INFINITY};
  float l_s[2] = {0.f, 0.f};
  f32x4 oacc[2][4];
  #pragma unroll
  for (int qs = 0; qs < 2; ++qs)
    #pragma unroll
    for (int mm = 0; mm < 4; ++mm) oacc[qs][mm] = {0.f, 0.f, 0.f, 0.f};

  const float sc = 1.0f / 256.0f;   // 1/TEMPERATURE

  for (int t = 0; t < SEQ / 64; ++t) {
    int kv0 = t * 64;
    // ---- stage K (linear LDS dest, inverse-swizzled global source) ----
    #pragma unroll
    for (int it = 0; it < 2; ++it) {
      int c = it * 256 + tid;
      int r = c >> 3, cg = c & 7;
      gload_lds16(K + hb + (size_t)(kv0 + r) * DMODEL + (cg ^ (r & 7)) * 8, &Kl[c * 8]);
    }
    // ---- stage V^T (reg transpose, swizzled write addr) ----
    {
      int kv = lane, dk0 = w * 16;
      const unsigned short* vp = V + hb + (size_t)(kv0 + kv) * DMODEL + dk0;
      u16x8 v0 = *(const u16x8*)vp;
      u16x8 v1 = *(const u16x8*)(vp + 8);
      int kvhi = kv >> 3, kvlo = kv & 7;
      #pragma unroll
      for (int e2 = 0; e2 < 8; ++e2) {
        int d = dk0 + e2;
        VT[d * 64 + ((kvhi ^ (d & 7)) << 3) + kvlo] = v0[e2];
      }
      #pragma unroll
      for (int e2 = 0; e2 < 8; ++e2) {
        int d = dk0 + 8 + e2;
        VT[d * 64 + ((kvhi ^ (d & 7)) << 3) + kvlo] = v1[e2];
      }
    }
    __syncthreads();

    // ---- hoisted K / V^T fragments (A-frag: row=l15, k=l16*8+j) ----
    bf16x8 kf[2][4], vf[2][4];
    #pragma unroll
    for (int kk = 0; kk < 2; ++kk)
      #pragma unroll
      for (int n = 0; n < 4; ++n)
        kf[kk][n] = *(const bf16x8*)&Kl[(n * 16 + l15) * 64 + (((kk * 4 + l16) ^ sw7) << 3)];
    #pragma unroll
    for (int kk = 0; kk < 2; ++kk)
      #pragma unroll
      for (int mm = 0; mm < 4; ++mm)
        vf[kk][mm] = *(const bf16x8*)&VT[(mm * 16 + l15) * 64 + (((kk * 4 + l16) ^ sw7) << 3)];

    #pragma unroll
    for (int qs = 0; qs < 2; ++qs) {
      // ---- S^T = K @ Q^T : lane owns q=l15, k = n*16 + l16*4 + r ----
      f32x4 sa[4];
      #pragma unroll
      for (int n = 0; n < 4; ++n) sa[n] = {0.f, 0.f, 0.f, 0.f};
      #pragma unroll
      for (int kk = 0; kk < 2; ++kk)
        #pragma unroll
        for (int n = 0; n < 4; ++n)
          sa[n] = __builtin_amdgcn_mfma_f32_16x16x32_bf16(kf[kk][n], qf[qs][kk], sa[n], 0, 0, 0);

      // ---- online softmax, lane-local ----
      float pmax = -INFINITY;
      #pragma unroll
      for (int n = 0; n < 4; ++n)
        #pragma unroll
        for (int r = 0; r < 4; ++r) { sa[n][r] *= sc; pmax = fmaxf(pmax, sa[n][r]); }
      pmax = fmaxf(pmax, __shfl_xor(pmax, 16));
      pmax = fmaxf(pmax, __shfl_xor(pmax, 32));
      float mn = fmaxf(m_s[qs], pmax);
      float corr = __expf(m_s[qs] - mn);
      m_s[qs] = mn;
      float rsum = 0.f;
      #pragma unroll
      for (int n = 0; n < 4; ++n)
        #pragma unroll
        for (int r = 0; r < 4; ++r) { sa[n][r] = __expf(sa[n][r] - mn); rsum += sa[n][r]; }
      rsum += __shfl_xor(rsum, 16);
      rsum += __shfl_xor(rsum, 32);
      l_s[qs] = l_s[qs] * corr + rsum;
      #pragma unroll
      for (int mm = 0; mm < 4; ++mm)
        #pragma unroll
        for (int r = 0; r < 4; ++r) oacc[qs][mm][r] *= corr;

      // ---- P^T -> per-wave LDS (swizzled b32 writes), read back as B-frag ----
      #pragma unroll
      for (int n = 0; n < 4; ++n) {
        #pragma unroll
        for (int r0 = 0; r0 < 4; r0 += 2) {
          uint32_t pw = (uint32_t)f2bf(sa[n][r0]) | ((uint32_t)f2bf(sa[n][r0 + 1]) << 16);
          int idx = l15 * 64 + (((n * 2 + (l16 >> 1)) ^ sw7) << 3) + (l16 & 1) * 4 + r0;
          *(uint32_t*)&Pl[w][idx] = pw;
        }
      }
      bf16x8 pf[2];
      #pragma unroll
      for (int kk = 0; kk < 2; ++kk)
        pf[kk] = *(const bf16x8*)&Pl[w][l15 * 64 + (((kk * 4 + l16) ^ sw7) << 3)];

      // ---- O^T += V^T @ P^T : accumulator col=q=l15, row d=mm*16+l16*4+r ----
      #pragma unroll
      for (int kk = 0; kk < 2; ++kk)
        #pragma unroll
        for (int mm = 0; mm < 4; ++mm)
          oacc[qs][mm] = __builtin_amdgcn_mfma_f32_16x16x32_bf16(vf[kk][mm], pf[kk], oacc[qs][mm], 0, 0, 0);
    }
    __syncthreads();
  }

  // ---- epilogue: normalize, pack 4 bf16 (8B) per (qs,mm) ----
  #pragma unroll
  for (int qs = 0; qs < 2; ++qs) {
    float inv = 1.0f / l_s[qs];
    #pragma unroll
    for (int mm = 0; mm < 4; ++mm) {
      u16x4 ov;
      #pragma unroll
      for (int r = 0; r < 4; ++r) ov[r] = f2bf(oacc[qs][mm][r] * inv);
      *(u16x4*)(O + hb + (size_t)(qrow + qs * 16 + l15) * DMODEL + mm * 16 + l16 * 4) = ov;
    }
  }
}

// ---------------------------------------------------------------------------
// Workspace layout (bytes)
// ---------------------------------------------------------------------------
static constexpr size_t EMB_OFF = 0;                         // 4*2048*4 = 32 KB
static constexpr size_t WQ_OFF  = 32768;
static constexpr size_t WK_OFF  = WQ_OFF + 2097152;
static constexpr size_t WV_OFF  = WK_OFF + 2097152;
static constexpr size_t WFC_OFF = WV_OFF + 2097152;
static constexpr size_t XBF_OFF = WFC_OFF + 2097152;         // 16 MB
static constexpr size_t KBF_OFF = XBF_OFF + 16777216;        // 16 MB
static constexpr size_t VBF_OFF = KBF_OFF + 16777216;        // 16 MB
static constexpr size_t QH_OFF  = VBF_OFF + 16777216;        // 16 MB
static constexpr size_t KH_OFF  = QH_OFF + 16777216;         // 16 MB
static constexpr size_t VH_OFF  = KH_OFF + 16777216;         // 16 MB
static constexpr size_t ATTN_OFF = KBF_OFF;                  // alias (k_bf dead after kh GEMM)

extern "C" void kernel_launch(void* const* d_in, const int* in_sizes, int n_in,
                              void* d_out, int out_size, void* d_ws, size_t ws_size,
                              hipStream_t stream) {
  const float* q     = (const float*)d_in[0];
  const float* k     = (const float*)d_in[1];
  const float* v     = (const float*)d_in[2];
  const float* t     = (const float*)d_in[3];
  const float* w_q   = (const float*)d_in[4];
  const float* w_k   = (const float*)d_in[5];
  const float* w_v   = (const float*)d_in[6];
  const float* w_fc  = (const float*)d_in[7];
  const float* ada_w = (const float*)d_in[8];
  const float* ada_b = (const float*)d_in[9];

  char* ws = (char*)d_ws;
  float* emb           = (float*)(ws + EMB_OFF);
  unsigned short* wqb  = (unsigned short*)(ws + WQ_OFF);
  unsigned short* wkb  = (unsigned short*)(ws + WK_OFF);
  unsigned short* wvb  = (unsigned short*)(ws + WV_OFF);
  unsigned short* wfcb = (unsigned short*)(ws + WFC_OFF);
  unsigned short* xbf  = (unsigned short*)(ws + XBF_OFF);
  unsigned short* kbf  = (unsigned short*)(ws + KBF_OFF);
  unsigned short* vbf  = (unsigned short*)(ws + VBF_OFF);
  unsigned short* qh   = (unsigned short*)(ws + QH_OFF);
  unsigned short* kh   = (unsigned short*)(ws + KH_OFF);
  unsigned short* vh   = (unsigned short*)(ws + VH_OFF);
  unsigned short* attn = (unsigned short*)(ws + ATTN_OFF);
  float* outf          = (float*)d_out;

  // 1) casts to bf16
  cast_f32_bf16<<<1024, 256, 0, stream>>>(w_q,  wqb,  1048576);
  cast_f32_bf16<<<1024, 256, 0, stream>>>(w_k,  wkb,  1048576);
  cast_f32_bf16<<<1024, 256, 0, stream>>>(w_v,  wvb,  1048576);
  cast_f32_bf16<<<1024, 256, 0, stream>>>(w_fc, wfcb, 1048576);
  cast_f32_bf16<<<8192, 256, 0, stream>>>(k, kbf, 8388608);
  cast_f32_bf16<<<8192, 256, 0, stream>>>(v, vbf, 8388608);

  // 2) adaLN scale/shift embedding
  ada_emb_kernel<<<dim3(8, 4), 256, 0, stream>>>(t, ada_w, ada_b, emb);

  // 3) adaLN on q -> x (bf16, also residual)
  adaln_kernel<<<8192, 256, 0, stream>>>(q, emb, xbf);

  // 4) QKV projections
  gemm_bt<0><<<dim3(8, 64), 256, 0, stream>>>(xbf, wqb, qh, nullptr, nullptr);
  gemm_bt<0><<<dim3(8, 64), 256, 0, stream>>>(kbf, wkb, kh, nullptr, nullptr);
  gemm_bt<0><<<dim3(8, 64), 256, 0, stream>>>(vbf, wvb, vh, nullptr, nullptr);

  // 5) attention (1D grid, XCD-swizzled)
  attn_kernel<<<1024, 256, 0, stream>>>(qh, kh, vh, attn);

  // 6) out-proj + residual (fp32 out)
  gemm_bt<1><<<dim3(8, 64), 256, 0, stream>>>(attn, wfcb, nullptr, xbf, outf);
}

// Round 4
// 435.651 us; speedup vs baseline: 1.3663x; 1.0559x over previous
//
#include <hip/hip_runtime.h>
#include <hip/hip_bf16.h>
#include <cstdint>

// ---------------------------------------------------------------------------
// Types
// ---------------------------------------------------------------------------
typedef short bf16x8 __attribute__((ext_vector_type(8)));     // 8 bf16 = 4 VGPRs (MFMA A/B frag)
typedef float f32x4  __attribute__((ext_vector_type(4)));     // MFMA C/D frag
typedef unsigned short u16x8 __attribute__((ext_vector_type(8)));
typedef unsigned short u16x4 __attribute__((ext_vector_type(4)));

#define SEQ    2048
#define BATCH  4
#define DMODEL 1024
#define NHEAD  16
#define DKH    64
#define MROWS  (BATCH * SEQ)      // 8192

__device__ __forceinline__ unsigned short f2bf(float f) {
  union { float f; uint32_t u; } x; x.f = f;
  uint32_t r = (x.u + 0x7fffu + ((x.u >> 16) & 1u)) >> 16;   // RNE
  return (unsigned short)r;
}
__device__ __forceinline__ float bf2f(unsigned short u) {
  union { uint32_t u; float f; } x; x.u = ((uint32_t)u) << 16;
  return x.f;
}
// HW packed f32x2 -> bf16x2 (RNE), 1 instr per pair
__device__ __forceinline__ uint32_t pack_bf2(float lo, float hi) {
  uint32_t r;
  asm("v_cvt_pk_bf16_f32 %0, %1, %2" : "=v"(r) : "v"(lo), "v"(hi));
  return r;
}
__device__ __forceinline__ void gload_lds16(const void* g, void* l) {
  __builtin_amdgcn_global_load_lds(
      (const __attribute__((address_space(1))) void*)g,
      (__attribute__((address_space(3))) void*)l, 16, 0, 0);
}

// ---------------------------------------------------------------------------
// Fused casts: 4 weight matrices (grid.y selects), and k+v (grid.y selects)
// ---------------------------------------------------------------------------
__global__ __launch_bounds__(256) void cast4_kernel(
    const float* __restrict__ s0, const float* __restrict__ s1,
    const float* __restrict__ s2, const float* __restrict__ s3,
    unsigned short* __restrict__ d0, unsigned short* __restrict__ d1,
    unsigned short* __restrict__ d2, unsigned short* __restrict__ d3) {
  int z = blockIdx.y;
  const float* in = z == 0 ? s0 : z == 1 ? s1 : z == 2 ? s2 : s3;
  unsigned short* out = z == 0 ? d0 : z == 1 ? d1 : z == 2 ? d2 : d3;
  int i = (blockIdx.x * 256 + threadIdx.x) * 4;
  float4 v = *(const float4*)(in + i);
  u16x4 o;
  o[0] = f2bf(v.x); o[1] = f2bf(v.y); o[2] = f2bf(v.z); o[3] = f2bf(v.w);
  *(u16x4*)(out + i) = o;
}

__global__ __launch_bounds__(256) void cast2_kernel(
    const float* __restrict__ s0, const float* __restrict__ s1,
    unsigned short* __restrict__ d0, unsigned short* __restrict__ d1) {
  int z = blockIdx.y;
  const float* in = z == 0 ? s0 : s1;
  unsigned short* out = z == 0 ? d0 : d1;
  int i = (blockIdx.x * 256 + threadIdx.x) * 4;
  float4 v = *(const float4*)(in + i);
  u16x4 o;
  o[0] = f2bf(v.x); o[1] = f2bf(v.y); o[2] = f2bf(v.z); o[3] = f2bf(v.w);
  *(u16x4*)(out + i) = o;
}

// ---------------------------------------------------------------------------
// adaLN embedding: emb[b][0:2048] = gelu(t[b]) @ ada_w.T + ada_b
// grid (8, 4) x 256
// ---------------------------------------------------------------------------
__global__ __launch_bounds__(256) void ada_emb_kernel(
    const float* __restrict__ t, const float* __restrict__ ada_w,
    const float* __restrict__ ada_b, float* __restrict__ emb) {
  int b = blockIdx.y;
  int j = blockIdx.x * 256 + threadIdx.x;          // 0..2047
  __shared__ float g[64];
  if (threadIdx.x < 64) {
    float x = t[b * 64 + threadIdx.x];
    g[threadIdx.x] = x * 0.5f * (1.0f + erff(x * 0.70710678118654752f)); // exact gelu
  }
  __syncthreads();
  float acc = ada_b[j];
  const float* wr = ada_w + (size_t)j * 64;
  #pragma unroll
  for (int i = 0; i < 64; ++i) acc += g[i] * wr[i];
  emb[b * 2048 + j] = acc;
}

// ---------------------------------------------------------------------------
// adaLN: x = LN(q)*(1+scale)+shift, stored bf16 (also the residual)
// one block per row; 256 threads x 4 elems
// ---------------------------------------------------------------------------
__global__ __launch_bounds__(256) void adaln_kernel(
    const float* __restrict__ q, const float* __restrict__ emb,
    unsigned short* __restrict__ xbf) {
  int row = blockIdx.x;                     // 0..8191
  int b = row >> 11;
  int tid = threadIdx.x;
  float4 x = ((const float4*)(q + (size_t)row * DMODEL))[tid];
  float s  = x.x + x.y + x.z + x.w;
  float s2 = x.x * x.x + x.y * x.y + x.z * x.z + x.w * x.w;
  #pragma unroll
  for (int off = 32; off > 0; off >>= 1) {
    s  += __shfl_down(s, off);
    s2 += __shfl_down(s2, off);
  }
  __shared__ float red[8];
  int w = tid >> 6;
  if ((tid & 63) == 0) { red[w * 2] = s; red[w * 2 + 1] = s2; }
  __syncthreads();
  s  = red[0] + red[2] + red[4] + red[6];
  s2 = red[1] + red[3] + red[5] + red[7];
  float mean = s * (1.0f / 1024.0f);
  float var  = s2 * (1.0f / 1024.0f) - mean * mean;
  float rs = rsqrtf(var + 1e-5f);
  float4 sc = ((const float4*)(emb + (size_t)b * 2048))[tid];
  float4 sh = ((const float4*)(emb + (size_t)b * 2048 + 1024))[tid];
  u16x4 o;
  o[0] = f2bf((x.x - mean) * rs * (1.0f + sc.x) + sh.x);
  o[1] = f2bf((x.y - mean) * rs * (1.0f + sc.y) + sh.y);
  o[2] = f2bf((x.z - mean) * rs * (1.0f + sc.z) + sh.z);
  o[3] = f2bf((x.w - mean) * rs * (1.0f + sc.w) + sh.w);
  ((u16x4*)(xbf + (size_t)row * DMODEL))[tid] = o;
}

// ---------------------------------------------------------------------------
// GEMM body: C[M,N] = A[M,K] @ Bw[N,K]^T (bf16 in, fp32 accum)
// 128x128 tile, BK=64, 4 waves (2x2 of 64x64).
// MODE 0: write bf16 C.  MODE 1: write f32 C + residual(bf16).
// ---------------------------------------------------------------------------
template <int MODE>
__device__ __forceinline__ void gemm_body(
    const unsigned short* A, const unsigned short* Bw,
    unsigned short* Cb, const unsigned short* resid, float* Cf) {
  __shared__ __align__(16) unsigned short Al[128 * 64];
  __shared__ __align__(16) unsigned short Bl[128 * 64];
  int tid = threadIdx.x;
  int lane = tid & 63, w = tid >> 6;
  int l15 = lane & 15, l16 = lane >> 4;
  int m0 = blockIdx.y * 128, n0 = blockIdx.x * 128;
  int wr = w >> 1, wc = w & 1;

  f32x4 acc[4][4];
  #pragma unroll
  for (int m = 0; m < 4; ++m)
    #pragma unroll
    for (int n = 0; n < 4; ++n) acc[m][n] = {0.f, 0.f, 0.f, 0.f};

  const unsigned short* Ab = A + (size_t)m0 * 1024;
  const unsigned short* Bb = Bw + (size_t)n0 * 1024;

  for (int kt = 0; kt < 16; ++kt) {
    int k0 = kt * 64;
    #pragma unroll
    for (int it = 0; it < 4; ++it) {
      int c = it * 256 + tid;
      int r = c >> 3, cg = c & 7;
      gload_lds16(Ab + (size_t)r * 1024 + k0 + cg * 8, &Al[c * 8]);
    }
    #pragma unroll
    for (int it = 0; it < 4; ++it) {
      int c = it * 256 + tid;
      int r = c >> 3, cg = c & 7;
      gload_lds16(Bb + (size_t)r * 1024 + k0 + cg * 8, &Bl[c * 8]);
    }
    __syncthreads();          // drains vmcnt -> staged data visible
    #pragma unroll
    for (int kk = 0; kk < 2; ++kk) {
      bf16x8 af[4], bfr[4];
      #pragma unroll
      for (int m = 0; m < 4; ++m)
        af[m] = *(const bf16x8*)&Al[(wr * 64 + m * 16 + l15) * 64 + kk * 32 + l16 * 8];
      #pragma unroll
      for (int n = 0; n < 4; ++n)
        bfr[n] = *(const bf16x8*)&Bl[(wc * 64 + n * 16 + l15) * 64 + kk * 32 + l16 * 8];
      __builtin_amdgcn_s_setprio(1);
      #pragma unroll
      for (int m = 0; m < 4; ++m)
        #pragma unroll
        for (int n = 0; n < 4; ++n)
          acc[m][n] = __builtin_amdgcn_mfma_f32_16x16x32_bf16(af[m], bfr[n], acc[m][n], 0, 0, 0);
      __builtin_amdgcn_s_setprio(0);
    }
    __syncthreads();
  }

  #pragma unroll
  for (int m = 0; m < 4; ++m) {
    #pragma unroll
    for (int r = 0; r < 4; ++r) {
      int row = m0 + wr * 64 + m * 16 + l16 * 4 + r;
      size_t base = (size_t)row * 1024 + n0 + wc * 64 + l15;
      #pragma unroll
      for (int n = 0; n < 4; ++n) {
        float val = acc[m][n][r];
        if (MODE == 0) {
          Cb[base + n * 16] = f2bf(val);
        } else {
          Cf[base + n * 16] = val + bf2f(resid[base + n * 16]);
        }
      }
    }
  }
}

// QKV fused: grid (8, 64, 3); z selects (A, B, C)
__global__ __launch_bounds__(256) void gemm_qkv_kernel(
    const unsigned short* xbf, const unsigned short* kbf, const unsigned short* vbf,
    const unsigned short* wq, const unsigned short* wk, const unsigned short* wv,
    unsigned short* qh, unsigned short* kh, unsigned short* vh) {
  int z = blockIdx.z;
  const unsigned short* A = z == 0 ? xbf : z == 1 ? kbf : vbf;
  const unsigned short* B = z == 0 ? wq  : z == 1 ? wk  : wv;
  unsigned short* C       = z == 0 ? qh  : z == 1 ? kh  : vh;
  gemm_body<0>(A, B, C, nullptr, nullptr);
}

__global__ __launch_bounds__(256) void gemm_fc_kernel(
    const unsigned short* attn, const unsigned short* wfc,
    const unsigned short* resid, float* outf) {
  gemm_body<1>(attn, wfc, nullptr, resid, outf);
}

// ---------------------------------------------------------------------------
// Flash attention v3: one block = (b, h, 128 q-rows); 4 waves x 32 rows each.
// Swapped-operand structure (S^T / O^T, lane-local softmax state) + this round:
//   * raw-score max tracking, exp2 with folded 1/T*log2(e) constant (fma+exp)
//   * T13 defer-max: rescale only when !__all(pmax - m <= THR)
//   * v_cvt_pk_bf16_f32 for P-pack and epilogue
//   * s_setprio(1) around MFMA clusters
// All LDS tiles XOR-swizzled at 16B-chunk granularity (chunk ^= row&7).
// Grid: 1024 blocks 1D, bijective XCD swizzle.
// ---------------------------------------------------------------------------
__global__ __launch_bounds__(256) void attn_kernel(
    const unsigned short* __restrict__ Q, const unsigned short* __restrict__ K,
    const unsigned short* __restrict__ V, unsigned short* __restrict__ O) {
  int tid = threadIdx.x;
  int lane = tid & 63, w = tid >> 6;
  int l15 = lane & 15, l16 = lane >> 4;
  int sw7 = l15 & 7;                       // read-side swizzle key (row&7)

  // XCD-aware decode: XCD k gets contiguous e-range -> 8 (b,h) pairs each
  int wgid = blockIdx.x;
  int e = (wgid & 7) * 128 + (wgid >> 3);
  int qt = e & 15, h = (e >> 4) & 15, b = e >> 8;

  __shared__ __align__(16) unsigned short Kl[64 * 64];      // 8 KB swizzled
  __shared__ __align__(16) unsigned short VT[64 * 64];      // 8 KB swizzled (d-major)
  __shared__ __align__(16) unsigned short Pl[4][16 * 64];   // 8 KB per-wave P^T

  size_t hb = (size_t)b * SEQ * DMODEL + (size_t)h * DKH;
  int qrow = qt * 128 + w * 32;

  // Q fragments (B-frag: col=q=l15, k = l16*8+j), 2 q-subtiles x 2 k-halves
  bf16x8 qf[2][2];
  #pragma unroll
  for (int qs = 0; qs < 2; ++qs)
    #pragma unroll
    for (int kk = 0; kk < 2; ++kk)
      qf[qs][kk] = *(const bf16x8*)(Q + hb + (size_t)(qrow + qs * 16 + l15) * DMODEL + kk * 32 + l16 * 8);

  const float csc = 1.44269504f / 256.0f;  // log2(e)/TEMPERATURE
  const float THR = 1280.0f;               // raw-score defer threshold (P <= 2^7.2)

  float m_s[2]  = {-INFINITY, -INFINITY};  // running max, RAW score units
  float mc_s[2] = {-INFINITY, -INFINITY};  // m * csc
  float l_s[2]  = {0.f, 0.f};
  f32x4 oacc[2][4];
  #pragma unroll
  for (int qs = 0; qs < 2; ++qs)
    #pragma unroll
    for (int mm = 0; mm < 4; ++mm) oacc[qs][mm] = {0.f, 0.f, 0.f, 0.f};

  for (int t = 0; t < SEQ / 64; ++t) {
    int kv0 = t * 64;
    // ---- stage K (linear LDS dest, inverse-swizzled global source) ----
    #pragma unroll
    for (int it = 0; it < 2; ++it) {
      int c = it * 256 + tid;
      int r = c >> 3, cg = c & 7;
      gload_lds16(K + hb + (size_t)(kv0 + r) * DMODEL + (cg ^ (r & 7)) * 8, &Kl[c * 8]);
    }
    // ---- stage V^T (reg transpose, swizzled write addr) ----
    {
      int kv = lane, dk0 = w * 16;
      const unsigned short* vp = V + hb + (size_t)(kv0 + kv) * DMODEL + dk0;
      u16x8 v0 = *(const u16x8*)vp;
      u16x8 v1 = *(const u16x8*)(vp + 8);
      int kvhi = kv >> 3, kvlo = kv & 7;
      #pragma unroll
      for (int e2 = 0; e2 < 8; ++e2) {
        int d = dk0 + e2;
        VT[d * 64 + ((kvhi ^ (d & 7)) << 3) + kvlo] = v0[e2];
      }
      #pragma unroll
      for (int e2 = 0; e2 < 8; ++e2) {
        int d = dk0 + 8 + e2;
        VT[d * 64 + ((kvhi ^ (d & 7)) << 3) + kvlo] = v1[e2];
      }
    }
    __syncthreads();

    // ---- hoisted K / V^T fragments (A-frag: row=l15, k=l16*8+j) ----
    bf16x8 kf[2][4], vf[2][4];
    #pragma unroll
    for (int kk = 0; kk < 2; ++kk)
      #pragma unroll
      for (int n = 0; n < 4; ++n)
        kf[kk][n] = *(const bf16x8*)&Kl[(n * 16 + l15) * 64 + (((kk * 4 + l16) ^ sw7) << 3)];
    #pragma unroll
    for (int kk = 0; kk < 2; ++kk)
      #pragma unroll
      for (int mm = 0; mm < 4; ++mm)
        vf[kk][mm] = *(const bf16x8*)&VT[(mm * 16 + l15) * 64 + (((kk * 4 + l16) ^ sw7) << 3)];

    #pragma unroll
    for (int qs = 0; qs < 2; ++qs) {
      // ---- S^T = K @ Q^T : lane owns q=l15, k = n*16 + l16*4 + r (RAW) ----
      f32x4 sa[4];
      #pragma unroll
      for (int n = 0; n < 4; ++n) sa[n] = {0.f, 0.f, 0.f, 0.f};
      __builtin_amdgcn_s_setprio(1);
      #pragma unroll
      for (int kk = 0; kk < 2; ++kk)
        #pragma unroll
        for (int n = 0; n < 4; ++n)
          sa[n] = __builtin_amdgcn_mfma_f32_16x16x32_bf16(kf[kk][n], qf[qs][kk], sa[n], 0, 0, 0);
      __builtin_amdgcn_s_setprio(0);

      // ---- online softmax, lane-local, raw units ----
      float pmax = fmaxf(fmaxf(fmaxf(sa[0][0], sa[0][1]), fmaxf(sa[0][2], sa[0][3])),
                         fmaxf(fmaxf(sa[1][0], sa[1][1]), fmaxf(sa[1][2], sa[1][3])));
      pmax = fmaxf(pmax, fmaxf(fmaxf(fmaxf(sa[2][0], sa[2][1]), fmaxf(sa[2][2], sa[2][3])),
                               fmaxf(fmaxf(sa[3][0], sa[3][1]), fmaxf(sa[3][2], sa[3][3]))));
      pmax = fmaxf(pmax, __shfl_xor(pmax, 16));
      pmax = fmaxf(pmax, __shfl_xor(pmax, 32));
      // T13 defer-max: only rescale when some lane's max grew past THR
      if (!__all(pmax - m_s[qs] <= THR)) {
        float mn = fmaxf(m_s[qs], pmax);
        float corr = __builtin_exp2f((m_s[qs] - mn) * csc);   // 0 on first tile
        m_s[qs] = mn;
        mc_s[qs] = mn * csc;
        l_s[qs] *= corr;
        #pragma unroll
        for (int mm = 0; mm < 4; ++mm)
          #pragma unroll
          for (int r = 0; r < 4; ++r) oacc[qs][mm][r] *= corr;
      }
      float mc = mc_s[qs];
      float rsum = 0.f;
      #pragma unroll
      for (int n = 0; n < 4; ++n)
        #pragma unroll
        for (int r = 0; r < 4; ++r) {
          sa[n][r] = __builtin_exp2f(__builtin_fmaf(sa[n][r], csc, -mc));
          rsum += sa[n][r];
        }
      rsum += __shfl_xor(rsum, 16);
      rsum += __shfl_xor(rsum, 32);
      l_s[qs] += rsum;

      // ---- P^T -> per-wave LDS (swizzled b32 writes, HW packed cvt) ----
      #pragma unroll
      for (int n = 0; n < 4; ++n) {
        #pragma unroll
        for (int r0 = 0; r0 < 4; r0 += 2) {
          uint32_t pw = pack_bf2(sa[n][r0], sa[n][r0 + 1]);
          int idx = l15 * 64 + (((n * 2 + (l16 >> 1)) ^ sw7) << 3) + (l16 & 1) * 4 + r0;
          *(uint32_t*)&Pl[w][idx] = pw;
        }
      }
      bf16x8 pf[2];
      #pragma unroll
      for (int kk = 0; kk < 2; ++kk)
        pf[kk] = *(const bf16x8*)&Pl[w][l15 * 64 + (((kk * 4 + l16) ^ sw7) << 3)];

      // ---- O^T += V^T @ P^T : accumulator col=q=l15, row d=mm*16+l16*4+r ----
      __builtin_amdgcn_s_setprio(1);
      #pragma unroll
      for (int kk = 0; kk < 2; ++kk)
        #pragma unroll
        for (int mm = 0; mm < 4; ++mm)
          oacc[qs][mm] = __builtin_amdgcn_mfma_f32_16x16x32_bf16(vf[kk][mm], pf[kk], oacc[qs][mm], 0, 0, 0);
      __builtin_amdgcn_s_setprio(0);
    }
    __syncthreads();
  }

  // ---- epilogue: normalize, HW-packed converts, 8B stores ----
  #pragma unroll
  for (int qs = 0; qs < 2; ++qs) {
    float inv = 1.0f / l_s[qs];
    #pragma unroll
    for (int mm = 0; mm < 4; ++mm) {
      uint32_t w0 = pack_bf2(oacc[qs][mm][0] * inv, oacc[qs][mm][1] * inv);
      uint32_t w1 = pack_bf2(oacc[qs][mm][2] * inv, oacc[qs][mm][3] * inv);
      uint2 ov = {w0, w1};
      *(uint2*)(O + hb + (size_t)(qrow + qs * 16 + l15) * DMODEL + mm * 16 + l16 * 4) = ov;
    }
  }
}

// ---------------------------------------------------------------------------
// Workspace layout (bytes)
// ---------------------------------------------------------------------------
static constexpr size_t EMB_OFF = 0;                         // 4*2048*4 = 32 KB
static constexpr size_t WQ_OFF  = 32768;
static constexpr size_t WK_OFF  = WQ_OFF + 2097152;
static constexpr size_t WV_OFF  = WK_OFF + 2097152;
static constexpr size_t WFC_OFF = WV_OFF + 2097152;
static constexpr size_t XBF_OFF = WFC_OFF + 2097152;         // 16 MB
static constexpr size_t KBF_OFF = XBF_OFF + 16777216;        // 16 MB
static constexpr size_t VBF_OFF = KBF_OFF + 16777216;        // 16 MB
static constexpr size_t QH_OFF  = VBF_OFF + 16777216;        // 16 MB
static constexpr size_t KH_OFF  = QH_OFF + 16777216;         // 16 MB
static constexpr size_t VH_OFF  = KH_OFF + 16777216;         // 16 MB
static constexpr size_t ATTN_OFF = KBF_OFF;                  // alias (k_bf dead after kh GEMM)

extern "C" void kernel_launch(void* const* d_in, const int* in_sizes, int n_in,
                              void* d_out, int out_size, void* d_ws, size_t ws_size,
                              hipStream_t stream) {
  const float* q     = (const float*)d_in[0];
  const float* k     = (const float*)d_in[1];
  const float* v     = (const float*)d_in[2];
  const float* t     = (const float*)d_in[3];
  const float* w_q   = (const float*)d_in[4];
  const float* w_k   = (const float*)d_in[5];
  const float* w_v   = (const float*)d_in[6];
  const float* w_fc  = (const float*)d_in[7];
  const float* ada_w = (const float*)d_in[8];
  const float* ada_b = (const float*)d_in[9];

  char* ws = (char*)d_ws;
  float* emb           = (float*)(ws + EMB_OFF);
  unsigned short* wqb  = (unsigned short*)(ws + WQ_OFF);
  unsigned short* wkb  = (unsigned short*)(ws + WK_OFF);
  unsigned short* wvb  = (unsigned short*)(ws + WV_OFF);
  unsigned short* wfcb = (unsigned short*)(ws + WFC_OFF);
  unsigned short* xbf  = (unsigned short*)(ws + XBF_OFF);
  unsigned short* kbf  = (unsigned short*)(ws + KBF_OFF);
  unsigned short* vbf  = (unsigned short*)(ws + VBF_OFF);
  unsigned short* qh   = (unsigned short*)(ws + QH_OFF);
  unsigned short* kh   = (unsigned short*)(ws + KH_OFF);
  unsigned short* vh   = (unsigned short*)(ws + VH_OFF);
  unsigned short* attn = (unsigned short*)(ws + ATTN_OFF);
  float* outf          = (float*)d_out;

  // 1) casts to bf16 (2 fused launches)
  cast4_kernel<<<dim3(1024, 4), 256, 0, stream>>>(w_q, w_k, w_v, w_fc, wqb, wkb, wvb, wfcb);
  cast2_kernel<<<dim3(8192, 2), 256, 0, stream>>>(k, v, kbf, vbf);

  // 2) adaLN scale/shift embedding
  ada_emb_kernel<<<dim3(8, 4), 256, 0, stream>>>(t, ada_w, ada_b, emb);

  // 3) adaLN on q -> x (bf16, also residual)
  adaln_kernel<<<8192, 256, 0, stream>>>(q, emb, xbf);

  // 4) QKV projections (one fused dispatch, 1536 blocks)
  gemm_qkv_kernel<<<dim3(8, 64, 3), 256, 0, stream>>>(xbf, kbf, vbf, wqb, wkb, wvb, qh, kh, vh);

  // 5) attention (1D grid, XCD-swizzled)
  attn_kernel<<<1024, 256, 0, stream>>>(qh, kh, vh, attn);

  // 6) out-proj + residual (fp32 out)
  gemm_fc_kernel<<<dim3(8, 64), 256, 0, stream>>>(attn, wfcb, xbf, outf);
}